// Round 5
// baseline (241.248 us; speedup 1.0000x reference)
//
#include <hip/hip_runtime.h>

typedef _Float16 f16x8 __attribute__((ext_vector_type(8)));
typedef _Float16 f16x4 __attribute__((ext_vector_type(4)));
typedef float f32x4 __attribute__((ext_vector_type(4)));

#define MFMA16(a, b, c) __builtin_amdgcn_mfma_f32_16x16x32_f16(a, b, c, 0, 0, 0)
#define SEGB 16777216ull

// 1/sqrt(32) * log2(e) folded into Wq at transpose; log2(e) folded into Wb.
#define QSCALE ((float)(1.4426950408889634 * 0.17677669529663687))
#define LOG2E 1.4426950408889634f

// ---------------------------------------------------------------------------
// Kernel 1: pure LayerNorm (fp32) -> z_ln f16.  Half-wave (32 lanes) per row.
// Tail blocks transpose+convert weights: mats 0..4 = {Wq*QSCALE, Wk, Wv, Wg,
// Wout} as Wt[n][k]; mat 5 = WbT[16][128] (*LOG2E, rows 4..15 zeroed).
// ---------------------------------------------------------------------------
__global__ __launch_bounds__(256) void k_ln(
    const float* __restrict__ z, const float* __restrict__ gamma,
    const float* __restrict__ beta,
    const float* __restrict__ Wq, const float* __restrict__ Wk,
    const float* __restrict__ Wv, const float* __restrict__ Wg,
    const float* __restrict__ Wout, const float* __restrict__ Wb,
    _Float16* __restrict__ zln, _Float16* __restrict__ WtAll)
{
  __shared__ _Float16 sw[32 * 136];
  int bid = blockIdx.x;
  if (bid < 8192) {
    int lane = threadIdx.x & 63;
    int w = threadIdx.x >> 6;
    int half = lane >> 5, lh = lane & 31;
    int row = bid * 8 + w * 2 + half;
    float4 v = ((const float4*)(z + (size_t)row * 128))[lh];
    float s = v.x + v.y + v.z + v.w;
    #pragma unroll
    for (int m = 1; m < 32; m <<= 1) s += __shfl_xor(s, m);
    float mu = s * 0.0078125f;
    float d0 = v.x - mu, d1 = v.y - mu, d2 = v.z - mu, d3 = v.w - mu;
    float q = d0 * d0 + d1 * d1 + d2 * d2 + d3 * d3;
    #pragma unroll
    for (int m = 1; m < 32; m <<= 1) q += __shfl_xor(q, m);
    float rs = rsqrtf(q * 0.0078125f + 1e-5f);
    float4 g4 = ((const float4*)gamma)[lh];
    float4 b4 = ((const float4*)beta)[lh];
    f16x4 o;
    o[0] = (_Float16)(d0 * rs * g4.x + b4.x);
    o[1] = (_Float16)(d1 * rs * g4.y + b4.y);
    o[2] = (_Float16)(d2 * rs * g4.z + b4.z);
    o[3] = (_Float16)(d3 * rs * g4.w + b4.w);
    *(f16x4*)(zln + (size_t)row * 128 + lh * 4) = o;
  } else if (bid < 8212) {
    int t = bid - 8192;               // 0..19 : 5 mats x 4 slabs of 32 n
    int mat = t >> 2, n0 = (t & 3) * 32;
    const float* src = (mat == 0) ? Wq : (mat == 1) ? Wk : (mat == 2) ? Wv
                       : (mat == 3) ? Wg : Wout;
    float sc = (mat == 0) ? QSCALE : 1.0f;
    for (int it = 0; it < 16; ++it) {
      int e = threadIdx.x + it * 256;   // 4096 elems
      int c = e >> 5, j = e & 31;
      sw[j * 136 + c] = (_Float16)(src[c * 128 + n0 + j] * sc);
    }
    __syncthreads();
    for (int it = 0; it < 2; ++it) {
      int ch = threadIdx.x + it * 256;  // 512 chunks of 8
      int n = ch >> 4, k8 = (ch & 15) * 8;
      *(int4*)(WtAll + mat * 16384 + (n0 + n) * 128 + k8) =
          *(const int4*)&sw[n * 136 + k8];
    }
  } else {
    _Float16* WbT = WtAll + 5 * 16384;  // [16][128]
    for (int it = 0; it < 8; ++it) {
      int e = threadIdx.x + it * 256;
      if (e < 2048) {
        int hrow = e >> 7, k = e & 127;
        float v = (hrow < 4) ? Wb[k * 4 + hrow] * LOG2E : 0.0f;
        WbT[hrow * 128 + k] = (_Float16)v;
      }
    }
  }
}

// ---------------------------------------------------------------------------
// Kernel 2: FUSED projections, operand-SWAPPED MFMA: D[m=col][n=row] so each
// lane owns one row and 4 consecutive cols in regs -> packed f16x4 stores
// (16x8B per mat instead of 256x2B).  64-row A-tile in LDS, loops {Q,K,V,G}
// + bias.  acc only 32 AGPR -> (256,4) safe.
// ---------------------------------------------------------------------------
__global__ __launch_bounds__(256, 4) void k_proj(
    const _Float16* __restrict__ A, const _Float16* __restrict__ WtAll,
    _Float16* __restrict__ Qb, _Float16* __restrict__ Kb,
    _Float16* __restrict__ Vb, _Float16* __restrict__ Gb,
    _Float16* __restrict__ biasP)
{
  __shared__ _Float16 sA[64 * 136];
  int m0 = blockIdx.x * 64;
  int tid = threadIdx.x, lane = tid & 63, w = tid >> 6;
  int lr = lane & 15, lg = lane >> 4;
  for (int it = 0; it < 4; ++it) {
    int ch = tid + it * 256;           // 1024 chunks of 8 halfs
    int r = ch >> 4, c8 = (ch & 15) * 8;
    *(int4*)&sA[r * 136 + c8] = *(const int4*)(A + (size_t)(m0 + r) * 128 + c8);
  }
  __syncthreads();
  f32x4 z4 = {0.f, 0.f, 0.f, 0.f};
  int myrow = m0 + w * 16 + lr;
  #pragma unroll 1
  for (int mat = 0; mat < 4; ++mat) {
    const _Float16* Bt = WtAll + mat * 16384;
    _Float16* outp = (mat == 0) ? Qb : (mat == 1) ? Kb : (mat == 2) ? Vb : Gb;
    f32x4 acc[8];
    #pragma unroll
    for (int nt = 0; nt < 8; ++nt) acc[nt] = z4;
    #pragma unroll
    for (int k0 = 0; k0 < 128; k0 += 32) {
      f16x8 af = *(const f16x8*)&sA[(w * 16 + lr) * 136 + k0 + lg * 8];
      f16x8 bf[8];
      #pragma unroll
      for (int nt = 0; nt < 8; ++nt)
        bf[nt] = *(const f16x8*)(Bt + (nt * 16 + lr) * 128 + k0 + lg * 8);
      #pragma unroll
      for (int nt = 0; nt < 8; ++nt)
        acc[nt] = MFMA16(bf[nt], af, acc[nt]);   // swapped: cols in regs
    }
    bool sig = (mat == 3);
    #pragma unroll
    for (int nt = 0; nt < 8; ++nt) {
      f16x4 o4;
      #pragma unroll
      for (int r = 0; r < 4; ++r) {
        float v = acc[nt][r];
        if (sig) v = 1.0f / (1.0f + __expf(-v));
        o4[r] = (_Float16)v;
      }
      *(f16x4*)(outp + (size_t)myrow * 128 + nt * 16 + lg * 4) = o4;
    }
  }
  // bias = z_ln @ WbT -> biasP[h][row] plain layout (h = lg*4+r, lg==0 only)
  {
    const _Float16* WbT = WtAll + 5 * 16384;
    f32x4 accb = z4;
    #pragma unroll
    for (int k0 = 0; k0 < 128; k0 += 32) {
      f16x8 bfb = *(const f16x8*)(WbT + lr * 128 + k0 + lg * 8);
      f16x8 afb = *(const f16x8*)&sA[(w * 16 + lr) * 136 + k0 + lg * 8];
      accb = MFMA16(bfb, afb, accb);
    }
    if (lg == 0) {
      #pragma unroll
      for (int r = 0; r < 4; ++r)
        biasP[r * 65536 + myrow] = (_Float16)accb[r];
    }
  }
}

// ---------------------------------------------------------------------------
// Kernel 3: attention per (i,h), all MFMAs operand-swapped: each lane owns
// one score/output row.  Streaming softmax: MFMA -> +bias(f16x4 loads) ->
// exp2(clamp) -> packed f16x4 P write to LDS + per-lane row sum (2 shuffles).
// O store packed f16x4.  64KB LDS, no barriers in the pass loop.
// ---------------------------------------------------------------------------
__global__ __launch_bounds__(256, 2) void k_attn(
    const _Float16* __restrict__ Qb, const _Float16* __restrict__ Kb,
    const _Float16* __restrict__ Vb, const _Float16* __restrict__ biasP,
    _Float16* __restrict__ O)
{
  __shared__ _Float16 sK[256 * 32];   // [k][d], chunk-swizzled
  __shared__ _Float16 sV[32 * 256];   // Vt [d][k], chunk-swizzled
  __shared__ _Float16 sP[64 * 256];   // P [j][k], chunk-swizzled
  int i = blockIdx.x, h = blockIdx.y;
  int tid = threadIdx.x;
  size_t base = ((size_t)i * 256) * 128 + h * 32;
  for (int it = 0; it < 4; ++it) {
    int ch = tid + it * 256;
    int r = ch >> 2, cx = ch & 3;
    int p = cx ^ ((r >> 1) & 3);
    *(int4*)&sK[r * 32 + p * 8] = *(const int4*)(Kb + base + (size_t)r * 128 + cx * 8);
  }
  for (int it = 0; it < 4; ++it) {
    int ch = tid + it * 256;
    int k = ch >> 2, d8 = (ch & 3) * 8;
    f16x8 tv = *(const f16x8*)(Vb + base + (size_t)k * 128 + d8);
    #pragma unroll
    for (int jj = 0; jj < 8; ++jj) {
      int d = d8 + jj;
      int p = (k >> 3) ^ (d & 7);
      sV[d * 256 + p * 8 + (k & 7)] = tv[jj];
    }
  }
  __syncthreads();
  int lane = tid & 63, w = tid >> 6;
  int lr = lane & 15, lg = lane >> 4;
  f32x4 z4 = {0.f, 0.f, 0.f, 0.f};
  const _Float16* bp = biasP + ((size_t)h << 16);
  for (int pass = 0; pass < 4; ++pass) {
    int jbase = pass * 64;
    int j = jbase + w * 16 + lr;        // this lane's row
    int row = w * 16 + lr;
    f16x8 aq = *(const f16x8*)(Qb + base + (size_t)j * 128 + lg * 8);
    const _Float16* brow = bp + j * 256;
    float sum = 0.f;
    #pragma unroll
    for (int kt = 0; kt < 16; ++kt) {
      int kr = kt * 16 + lr;
      int p = lg ^ ((kr >> 1) & 3);
      f16x8 bk = *(const f16x8*)&sK[kr * 32 + p * 8];
      f32x4 s = MFMA16(bk, aq, z4);     // swapped: D[m=kcol][n=jrow]
      f16x4 bb = *(const f16x4*)(brow + kt * 16 + lg * 4);
      f16x4 pk;
      #pragma unroll
      for (int r = 0; r < 4; ++r) {
        float sv = fminf(s[r] + (float)bb[r], 14.f);  // f16-safe clamp
        float e = exp2f(sv);
        sum += e;
        pk[r] = (_Float16)e;            // unnormalized
      }
      int ch = kt * 2 + (lg >> 1);
      *(f16x4*)&sP[row * 256 + (ch ^ (row & 7)) * 8 + (lg & 1) * 4] = pk;
    }
    sum += __shfl_xor(sum, 16);
    sum += __shfl_xor(sum, 32);
    float rinv = 1.0f / sum;
    // O = P @ V, swapped: D[m=d][n=jrow], cols-in-regs
    f32x4 oacc[2] = {z4, z4};
    #pragma unroll
    for (int ks = 0; ks < 8; ++ks) {
      int c = ks * 4 + lg;
      f16x8 ap = *(const f16x8*)&sP[row * 256 + (c ^ (row & 7)) * 8];
      #pragma unroll
      for (int nt = 0; nt < 2; ++nt) {
        int d = nt * 16 + lr;
        f16x8 bv = *(const f16x8*)&sV[d * 256 + (c ^ (d & 7)) * 8];
        oacc[nt] = MFMA16(bv, ap, oacc[nt]);
      }
    }
    #pragma unroll
    for (int nt = 0; nt < 2; ++nt) {
      f16x4 o4;
      #pragma unroll
      for (int r = 0; r < 4; ++r) o4[r] = (_Float16)(oacc[nt][r] * rinv);
      *(f16x4*)(O + base + (size_t)j * 128 + nt * 16 + lg * 4) = o4;
    }
  }
}

// ---------------------------------------------------------------------------
// Kernel 4: out = (O .* G) @ Wout, fp32 output.  Swapped MFMA -> float4
// stores (8x16B per thread instead of 32x4B).  64-row tiles, grid 1024.
// ---------------------------------------------------------------------------
__global__ __launch_bounds__(256, 4) void k_outp(
    const _Float16* __restrict__ O, const _Float16* __restrict__ G,
    const _Float16* __restrict__ Bt, float* __restrict__ out)
{
  int m0 = blockIdx.x * 64;
  int tid = threadIdx.x, lane = tid & 63, w = tid >> 6;
  int lr = lane & 15, lg = lane >> 4;
  int myrow = m0 + w * 16 + lr;
  f32x4 z4 = {0.f, 0.f, 0.f, 0.f};
  f32x4 acc[8];
  #pragma unroll
  for (int nt = 0; nt < 8; ++nt) acc[nt] = z4;
  #pragma unroll
  for (int k0 = 0; k0 < 128; k0 += 32) {
    size_t a = (size_t)myrow * 128 + k0 + lg * 8;
    f16x8 o8 = *(const f16x8*)(O + a);
    f16x8 g8 = *(const f16x8*)(G + a);
    f16x8 af = o8 * g8;
    f16x8 bf[8];
    #pragma unroll
    for (int nt = 0; nt < 8; ++nt)
      bf[nt] = *(const f16x8*)(Bt + (nt * 16 + lr) * 128 + k0 + lg * 8);
    #pragma unroll
    for (int nt = 0; nt < 8; ++nt)
      acc[nt] = MFMA16(bf[nt], af, acc[nt]);   // swapped: cols in regs
  }
  #pragma unroll
  for (int nt = 0; nt < 8; ++nt) {
    float4 o4;
    o4.x = acc[nt][0]; o4.y = acc[nt][1];
    o4.z = acc[nt][2]; o4.w = acc[nt][3];
    *(float4*)(out + (size_t)myrow * 128 + nt * 16 + lg * 4) = o4;
  }
}

// ---------------------------------------------------------------------------
extern "C" void kernel_launch(void* const* d_in, const int* in_sizes, int n_in,
                              void* d_out, int out_size, void* d_ws, size_t ws_size,
                              hipStream_t stream) {
  (void)in_sizes; (void)n_in; (void)out_size; (void)ws_size;
  const float* z    = (const float*)d_in[0];
  const float* gam  = (const float*)d_in[1];
  const float* bet  = (const float*)d_in[2];
  const float* Wq   = (const float*)d_in[3];
  const float* Wk   = (const float*)d_in[4];
  const float* Wv   = (const float*)d_in[5];
  const float* Wb   = (const float*)d_in[6];
  const float* Wg   = (const float*)d_in[7];
  const float* Wout = (const float*)d_in[8];

  char* ws = (char*)d_ws;
  _Float16* zln   = (_Float16*)(ws);                 // 16MB; reused as O
  _Float16* Qb    = (_Float16*)(ws + SEGB);
  _Float16* Kb    = (_Float16*)(ws + SEGB * 2);
  _Float16* Vb    = (_Float16*)(ws + SEGB * 3);
  _Float16* Gb    = (_Float16*)(ws + SEGB * 4);
  _Float16* biasP = (_Float16*)(ws + SEGB * 5);      // 512KB [4][65536] f16
  _Float16* WtAll = (_Float16*)(ws + SEGB * 5 + 1048576);  // 5*16384 + 2048

  k_ln<<<8213, 256, 0, stream>>>(z, gam, bet, Wq, Wk, Wv, Wg, Wout, Wb,
                                 zln, WtAll);
  k_proj<<<1024, 256, 0, stream>>>(zln, WtAll, Qb, Kb, Vb, Gb, biasP);
  k_attn<<<dim3(256, 4), 256, 0, stream>>>(Qb, Kb, Vb, biasP, zln);
  k_outp<<<1024, 256, 0, stream>>>(zln, Gb, WtAll + 4 * 16384, (float*)d_out);
}

// Round 6
// 208.509 us; speedup vs baseline: 1.1570x; 1.1570x over previous
//
#include <hip/hip_runtime.h>

typedef _Float16 f16x8 __attribute__((ext_vector_type(8)));
typedef _Float16 f16x4 __attribute__((ext_vector_type(4)));
typedef float f32x4 __attribute__((ext_vector_type(4)));

#define MFMA16(a, b, c) __builtin_amdgcn_mfma_f32_16x16x32_f16(a, b, c, 0, 0, 0)
#define SEGB 16777216ull

// 1/sqrt(32) * log2(e) folded into Wq at transpose; log2(e) folded into Wb.
#define QSCALE ((float)(1.4426950408889634 * 0.17677669529663687))
#define LOG2E 1.4426950408889634f

// ---------------------------------------------------------------------------
// Kernel 1: pure LayerNorm (fp32) -> z_ln f16.  Half-wave (32 lanes) per row.
// Tail blocks transpose+convert weights: mats 0..4 = {Wq*QSCALE, Wk, Wv, Wg,
// Wout} as Wt[n][k]; mat 5 = WbT[16][128] (*LOG2E, rows 4..15 zeroed).
// ---------------------------------------------------------------------------
__global__ __launch_bounds__(256) void k_ln(
    const float* __restrict__ z, const float* __restrict__ gamma,
    const float* __restrict__ beta,
    const float* __restrict__ Wq, const float* __restrict__ Wk,
    const float* __restrict__ Wv, const float* __restrict__ Wg,
    const float* __restrict__ Wout, const float* __restrict__ Wb,
    _Float16* __restrict__ zln, _Float16* __restrict__ WtAll)
{
  __shared__ _Float16 sw[32 * 136];
  int bid = blockIdx.x;
  if (bid < 8192) {
    int lane = threadIdx.x & 63;
    int w = threadIdx.x >> 6;
    int half = lane >> 5, lh = lane & 31;
    int row = bid * 8 + w * 2 + half;
    float4 v = ((const float4*)(z + (size_t)row * 128))[lh];
    float s = v.x + v.y + v.z + v.w;
    #pragma unroll
    for (int m = 1; m < 32; m <<= 1) s += __shfl_xor(s, m);
    float mu = s * 0.0078125f;
    float d0 = v.x - mu, d1 = v.y - mu, d2 = v.z - mu, d3 = v.w - mu;
    float q = d0 * d0 + d1 * d1 + d2 * d2 + d3 * d3;
    #pragma unroll
    for (int m = 1; m < 32; m <<= 1) q += __shfl_xor(q, m);
    float rs = rsqrtf(q * 0.0078125f + 1e-5f);
    float4 g4 = ((const float4*)gamma)[lh];
    float4 b4 = ((const float4*)beta)[lh];
    f16x4 o;
    o[0] = (_Float16)(d0 * rs * g4.x + b4.x);
    o[1] = (_Float16)(d1 * rs * g4.y + b4.y);
    o[2] = (_Float16)(d2 * rs * g4.z + b4.z);
    o[3] = (_Float16)(d3 * rs * g4.w + b4.w);
    *(f16x4*)(zln + (size_t)row * 128 + lh * 4) = o;
  } else if (bid < 8212) {
    int t = bid - 8192;               // 0..19 : 5 mats x 4 slabs of 32 n
    int mat = t >> 2, n0 = (t & 3) * 32;
    const float* src = (mat == 0) ? Wq : (mat == 1) ? Wk : (mat == 2) ? Wv
                       : (mat == 3) ? Wg : Wout;
    float sc = (mat == 0) ? QSCALE : 1.0f;
    for (int it = 0; it < 16; ++it) {
      int e = threadIdx.x + it * 256;   // 4096 elems
      int c = e >> 5, j = e & 31;
      sw[j * 136 + c] = (_Float16)(src[c * 128 + n0 + j] * sc);
    }
    __syncthreads();
    for (int it = 0; it < 2; ++it) {
      int ch = threadIdx.x + it * 256;  // 512 chunks of 8
      int n = ch >> 4, k8 = (ch & 15) * 8;
      *(int4*)(WtAll + mat * 16384 + (n0 + n) * 128 + k8) =
          *(const int4*)&sw[n * 136 + k8];
    }
  } else {
    _Float16* WbT = WtAll + 5 * 16384;  // [16][128]
    for (int it = 0; it < 8; ++it) {
      int e = threadIdx.x + it * 256;
      if (e < 2048) {
        int hrow = e >> 7, k = e & 127;
        float v = (hrow < 4) ? Wb[k * 4 + hrow] * LOG2E : 0.0f;
        WbT[hrow * 128 + k] = (_Float16)v;
      }
    }
  }
}

// ---------------------------------------------------------------------------
// Kernel 2: FUSED projections, NO LDS, swapped MFMA.  128-row tile: each
// wave owns 32 rows (af[2] straight from global, L1 covers x4 mat reuse);
// bf[8] amortized over 2 af (2:1 MFMA:load).  No barriers.  Packed f16x4
// stores.  (256,3): 64 AGPR + ~75 arch < 168 cap.
// ---------------------------------------------------------------------------
__global__ __launch_bounds__(256, 3) void k_proj(
    const _Float16* __restrict__ A, const _Float16* __restrict__ WtAll,
    _Float16* __restrict__ Qb, _Float16* __restrict__ Kb,
    _Float16* __restrict__ Vb, _Float16* __restrict__ Gb,
    _Float16* __restrict__ biasP)
{
  int m0 = blockIdx.x * 128;
  int tid = threadIdx.x, lane = tid & 63, w = tid >> 6;
  int lr = lane & 15, lg = lane >> 4;
  int r0 = m0 + w * 32;
  const _Float16* arow0 = A + (size_t)(r0 + lr) * 128 + lg * 8;
  const _Float16* arow1 = arow0 + 16 * 128;
  f32x4 z4 = {0.f, 0.f, 0.f, 0.f};
  #pragma unroll 1
  for (int mat = 0; mat < 4; ++mat) {
    const _Float16* Bt = WtAll + mat * 16384;
    _Float16* outp = (mat == 0) ? Qb : (mat == 1) ? Kb : (mat == 2) ? Vb : Gb;
    f32x4 acc[2][8];
    #pragma unroll
    for (int g = 0; g < 2; ++g)
      #pragma unroll
      for (int nt = 0; nt < 8; ++nt) acc[g][nt] = z4;
    #pragma unroll
    for (int k0 = 0; k0 < 128; k0 += 32) {
      f16x8 af0 = *(const f16x8*)(arow0 + k0);
      f16x8 af1 = *(const f16x8*)(arow1 + k0);
      f16x8 bf[8];
      #pragma unroll
      for (int nt = 0; nt < 8; ++nt)
        bf[nt] = *(const f16x8*)(Bt + (nt * 16 + lr) * 128 + k0 + lg * 8);
      #pragma unroll
      for (int nt = 0; nt < 8; ++nt) {
        acc[0][nt] = MFMA16(bf[nt], af0, acc[0][nt]);   // swapped: cols in regs
        acc[1][nt] = MFMA16(bf[nt], af1, acc[1][nt]);
      }
    }
    bool sig = (mat == 3);
    #pragma unroll
    for (int g = 0; g < 2; ++g)
      #pragma unroll
      for (int nt = 0; nt < 8; ++nt) {
        f16x4 o4;
        #pragma unroll
        for (int r = 0; r < 4; ++r) {
          float v = acc[g][nt][r];
          if (sig) v = 1.0f / (1.0f + __expf(-v));
          o4[r] = (_Float16)v;
        }
        *(f16x4*)(outp + (size_t)(r0 + g * 16 + lr) * 128 + nt * 16 + lg * 4) = o4;
      }
  }
  // bias = z_ln @ WbT -> biasP[h][row] (h = lg*4+r, stored by lg==0 lanes)
  {
    const _Float16* WbT = WtAll + 5 * 16384;
    f32x4 accb[2] = {z4, z4};
    #pragma unroll
    for (int k0 = 0; k0 < 128; k0 += 32) {
      f16x8 bfb = *(const f16x8*)(WbT + lr * 128 + k0 + lg * 8);
      accb[0] = MFMA16(bfb, *(const f16x8*)(arow0 + k0), accb[0]);
      accb[1] = MFMA16(bfb, *(const f16x8*)(arow1 + k0), accb[1]);
    }
    if (lg == 0) {
      #pragma unroll
      for (int g = 0; g < 2; ++g)
        #pragma unroll
        for (int r = 0; r < 4; ++r)
          biasP[r * 65536 + r0 + g * 16 + lr] = (_Float16)accb[g][r];
    }
  }
}

// ---------------------------------------------------------------------------
// Kernel 3: attention per (i,h), swapped MFMAs, streaming softmax, fused
// GATING: OG = O * G * rinv stored packed f16x4.  64KB LDS.
// ---------------------------------------------------------------------------
__global__ __launch_bounds__(256, 2) void k_attn(
    const _Float16* __restrict__ Qb, const _Float16* __restrict__ Kb,
    const _Float16* __restrict__ Vb, const _Float16* __restrict__ Gb,
    const _Float16* __restrict__ biasP, _Float16* __restrict__ OG)
{
  __shared__ _Float16 sK[256 * 32];   // [k][d], chunk-swizzled
  __shared__ _Float16 sV[32 * 256];   // Vt [d][k], chunk-swizzled
  __shared__ _Float16 sP[64 * 256];   // P [j][k], chunk-swizzled
  int i = blockIdx.x, h = blockIdx.y;
  int tid = threadIdx.x;
  size_t base = ((size_t)i * 256) * 128 + h * 32;
  for (int it = 0; it < 4; ++it) {
    int ch = tid + it * 256;
    int r = ch >> 2, cx = ch & 3;
    int p = cx ^ ((r >> 1) & 3);
    *(int4*)&sK[r * 32 + p * 8] = *(const int4*)(Kb + base + (size_t)r * 128 + cx * 8);
  }
  for (int it = 0; it < 4; ++it) {
    int ch = tid + it * 256;
    int k = ch >> 2, d8 = (ch & 3) * 8;
    f16x8 tv = *(const f16x8*)(Vb + base + (size_t)k * 128 + d8);
    #pragma unroll
    for (int jj = 0; jj < 8; ++jj) {
      int d = d8 + jj;
      int p = (k >> 3) ^ (d & 7);
      sV[d * 256 + p * 8 + (k & 7)] = tv[jj];
    }
  }
  __syncthreads();
  int lane = tid & 63, w = tid >> 6;
  int lr = lane & 15, lg = lane >> 4;
  f32x4 z4 = {0.f, 0.f, 0.f, 0.f};
  const _Float16* bp = biasP + ((size_t)h << 16);
  for (int pass = 0; pass < 4; ++pass) {
    int jbase = pass * 64;
    int j = jbase + w * 16 + lr;        // this lane's row
    int row = w * 16 + lr;
    f16x8 aq = *(const f16x8*)(Qb + base + (size_t)j * 128 + lg * 8);
    const _Float16* brow = bp + j * 256;
    float sum = 0.f;
    #pragma unroll
    for (int kt = 0; kt < 16; ++kt) {
      int kr = kt * 16 + lr;
      int p = lg ^ ((kr >> 1) & 3);
      f16x8 bk = *(const f16x8*)&sK[kr * 32 + p * 8];
      f32x4 s = MFMA16(bk, aq, z4);     // swapped: D[m=kcol][n=jrow]
      f16x4 bb = *(const f16x4*)(brow + kt * 16 + lg * 4);
      f16x4 pk;
      #pragma unroll
      for (int r = 0; r < 4; ++r) {
        float sv = fminf(s[r] + (float)bb[r], 14.f);  // f16-safe clamp
        float e = exp2f(sv);
        sum += e;
        pk[r] = (_Float16)e;            // unnormalized
      }
      int ch = kt * 2 + (lg >> 1);
      *(f16x4*)&sP[row * 256 + (ch ^ (row & 7)) * 8 + (lg & 1) * 4] = pk;
    }
    sum += __shfl_xor(sum, 16);
    sum += __shfl_xor(sum, 32);
    float rinv = 1.0f / sum;
    // O = P @ V, swapped: D[m=d][n=jrow], cols-in-regs
    f32x4 oacc[2] = {z4, z4};
    #pragma unroll
    for (int ks = 0; ks < 8; ++ks) {
      int c = ks * 4 + lg;
      f16x8 ap = *(const f16x8*)&sP[row * 256 + (c ^ (row & 7)) * 8];
      #pragma unroll
      for (int nt = 0; nt < 2; ++nt) {
        int d = nt * 16 + lr;
        f16x8 bv = *(const f16x8*)&sV[d * 256 + (c ^ (d & 7)) * 8];
        oacc[nt] = MFMA16(bv, ap, oacc[nt]);
      }
    }
    #pragma unroll
    for (int nt = 0; nt < 2; ++nt) {
      f16x4 g4 = *(const f16x4*)(Gb + base + (size_t)j * 128 + nt * 16 + lg * 4);
      f16x4 o4;
      #pragma unroll
      for (int r = 0; r < 4; ++r)
        o4[r] = (_Float16)(oacc[nt][r] * rinv * (float)g4[r]);
      *(f16x4*)(OG + base + (size_t)j * 128 + nt * 16 + lg * 4) = o4;
    }
  }
}

// ---------------------------------------------------------------------------
// Kernel 4: out = OG @ Wout, fp32 output.  128-row no-LDS swapped mirror of
// k_proj; reads pre-gated OG only.  float4 stores.
// ---------------------------------------------------------------------------
__global__ __launch_bounds__(256, 3) void k_outp(
    const _Float16* __restrict__ OG, const _Float16* __restrict__ Bt,
    float* __restrict__ out)
{
  int m0 = blockIdx.x * 128;
  int tid = threadIdx.x, lane = tid & 63, w = tid >> 6;
  int lr = lane & 15, lg = lane >> 4;
  int r0 = m0 + w * 32;
  const _Float16* arow0 = OG + (size_t)(r0 + lr) * 128 + lg * 8;
  const _Float16* arow1 = arow0 + 16 * 128;
  f32x4 z4 = {0.f, 0.f, 0.f, 0.f};
  f32x4 acc[2][8];
  #pragma unroll
  for (int g = 0; g < 2; ++g)
    #pragma unroll
    for (int nt = 0; nt < 8; ++nt) acc[g][nt] = z4;
  #pragma unroll
  for (int k0 = 0; k0 < 128; k0 += 32) {
    f16x8 af0 = *(const f16x8*)(arow0 + k0);
    f16x8 af1 = *(const f16x8*)(arow1 + k0);
    f16x8 bf[8];
    #pragma unroll
    for (int nt = 0; nt < 8; ++nt)
      bf[nt] = *(const f16x8*)(Bt + (nt * 16 + lr) * 128 + k0 + lg * 8);
    #pragma unroll
    for (int nt = 0; nt < 8; ++nt) {
      acc[0][nt] = MFMA16(bf[nt], af0, acc[0][nt]);
      acc[1][nt] = MFMA16(bf[nt], af1, acc[1][nt]);
    }
  }
  #pragma unroll
  for (int g = 0; g < 2; ++g)
    #pragma unroll
    for (int nt = 0; nt < 8; ++nt) {
      float4 o4;
      o4.x = acc[g][nt][0]; o4.y = acc[g][nt][1];
      o4.z = acc[g][nt][2]; o4.w = acc[g][nt][3];
      *(float4*)(out + (size_t)(r0 + g * 16 + lr) * 128 + nt * 16 + lg * 4) = o4;
    }
}

// ---------------------------------------------------------------------------
extern "C" void kernel_launch(void* const* d_in, const int* in_sizes, int n_in,
                              void* d_out, int out_size, void* d_ws, size_t ws_size,
                              hipStream_t stream) {
  (void)in_sizes; (void)n_in; (void)out_size; (void)ws_size;
  const float* z    = (const float*)d_in[0];
  const float* gam  = (const float*)d_in[1];
  const float* bet  = (const float*)d_in[2];
  const float* Wq   = (const float*)d_in[3];
  const float* Wk   = (const float*)d_in[4];
  const float* Wv   = (const float*)d_in[5];
  const float* Wb   = (const float*)d_in[6];
  const float* Wg   = (const float*)d_in[7];
  const float* Wout = (const float*)d_in[8];

  char* ws = (char*)d_ws;
  _Float16* zln   = (_Float16*)(ws);                 // 16MB; reused as OG
  _Float16* Qb    = (_Float16*)(ws + SEGB);
  _Float16* Kb    = (_Float16*)(ws + SEGB * 2);
  _Float16* Vb    = (_Float16*)(ws + SEGB * 3);
  _Float16* Gb    = (_Float16*)(ws + SEGB * 4);
  _Float16* biasP = (_Float16*)(ws + SEGB * 5);      // 512KB [4][65536] f16
  _Float16* WtAll = (_Float16*)(ws + SEGB * 5 + 1048576);  // 5*16384 + 2048

  k_ln<<<8213, 256, 0, stream>>>(z, gam, bet, Wq, Wk, Wv, Wg, Wout, Wb,
                                 zln, WtAll);
  k_proj<<<512, 256, 0, stream>>>(zln, WtAll, Qb, Kb, Vb, Gb, biasP);
  k_attn<<<dim3(256, 4), 256, 0, stream>>>(Qb, Kb, Vb, Gb, biasP, zln);
  k_outp<<<512, 256, 0, stream>>>(zln, WtAll + 4 * 16384, (float*)d_out);
}